// Round 18
// baseline (97.696 us; speedup 1.0000x reference)
//
#include <hip/hip_runtime.h>

namespace {

constexpr int N = 20;                  // NEIGHBOR_SIZE
constexpr int ROWS = 5;                // rows per lane
constexpr int NP = N / 2;              // 10 column-pairs per row
constexpr int GROUPS = 16;             // 4-lane quads per wave = 16 matrices/tile
constexpr int TILE = 2;                // t0 from global->regs, t1 via LDS
constexpr int WAVES_PER_BLOCK = 4;     // 256 threads
constexpr int MATS_PER_WAVE = GROUPS * TILE;                     // 32
constexpr int MATS_PER_BLOCK = MATS_PER_WAVE * WAVES_PER_BLOCK;  // 128 -> 1563 blocks
constexpr int PTS_FLOATS = GROUPS * 2 * N;   // 640 floats = 2560 B t1 points
constexpr int WBUF_FLOATS = 4 * N * N;       // 1600 floats transpose buffer
constexpr float SIGMA_SQ = 1.0f;
constexpr float PHI = 0.5f;
constexpr float TAU = 0.1f;
constexpr float CSCALE = 0.72134752f;  // PHI * log2(e)

typedef float f32x2 __attribute__((ext_vector_type(2)));

#define LGKM_FENCE() asm volatile("s_waitcnt lgkmcnt(0)" ::: "memory")
#define SCHED_FENCE() __builtin_amdgcn_sched_barrier(0)

// Broadcast lane SRC of each 4-lane quad to all 4 lanes: DPP quad_perm.
template <int SRC>
__device__ __forceinline__ float qbcast(float x) {
  constexpr int CTRL = SRC * 0x55;
  return __builtin_bit_cast(
      float, __builtin_amdgcn_mov_dpp(__builtin_bit_cast(int, x), CTRL, 0xF,
                                      0xF, true));
}

// One Gauss-Jordan step on the PACKED tableau a2[5][10] (v_pk_fma_f32).
// K template => every register index compile-time (rule #20).
template <int K>
__device__ __forceinline__ void gj_step(f32x2 (&a2)[ROWS][NP], int o,
                                        const float (&ofl)[4]) {
  constexpr int KO = K / ROWS;
  constexpr int KR = K % ROWS;
  constexpr int KP = K / 2;
  constexpr int KE = K % 2;

  f32x2 r2[NP];
#pragma unroll
  for (int q = 0; q < NP; ++q) {
    r2[q].x = qbcast<KO>(a2[KR][q].x);
    r2[q].y = qbcast<KO>(a2[KR][q].y);
  }
  const float rK = KE ? r2[KP].y : r2[KP].x;
  const float ip = __builtin_amdgcn_rcpf(rK);
  const float fpiv = 1.0f - ip;

#pragma unroll
  for (int rr = 0; rr < ROWS; ++rr) {
    const float aK = KE ? a2[rr][KP].y : a2[rr][KP].x;
    float f = aK * ip;
    if (rr == KR) f = (o == KO) ? fpiv : f;
    const float nf = -f;
    const f32x2 nf2 = {nf, nf};
#pragma unroll
    for (int q = 0; q < NP; ++q) {
      a2[rr][q] = __builtin_elementwise_fma(nf2, r2[q], a2[rr][q]);
    }
    if (KE) a2[rr][KP].y = nf; else a2[rr][KP].x = nf;
  }
  if (KE) a2[KR][KP].y += ofl[KO]; else a2[KR][KP].x += ofl[KO];
}

__device__ __forceinline__ void gj_all(f32x2 (&a2)[ROWS][NP], int o,
                                       const float (&ofl)[4]) {
  __builtin_amdgcn_s_setprio(1);
  gj_step<0>(a2, o, ofl);  gj_step<1>(a2, o, ofl);  gj_step<2>(a2, o, ofl);
  gj_step<3>(a2, o, ofl);  gj_step<4>(a2, o, ofl);  gj_step<5>(a2, o, ofl);
  gj_step<6>(a2, o, ofl);  gj_step<7>(a2, o, ofl);  gj_step<8>(a2, o, ofl);
  gj_step<9>(a2, o, ofl);  gj_step<10>(a2, o, ofl); gj_step<11>(a2, o, ofl);
  gj_step<12>(a2, o, ofl); gj_step<13>(a2, o, ofl); gj_step<14>(a2, o, ofl);
  gj_step<15>(a2, o, ofl); gj_step<16>(a2, o, ofl); gj_step<17>(a2, o, ofl);
  gj_step<18>(a2, o, ofl); gj_step<19>(a2, o, ofl);
  __builtin_amdgcn_s_setprio(0);
}

// Build my 5 rows (packed pairs) from px2/py2/myx/myy registers.
__device__ __forceinline__ void build_cov(f32x2 (&a2)[ROWS][NP],
                                          const f32x2 (&px2)[NP],
                                          const f32x2 (&py2)[NP],
                                          const float (&myx)[ROWS],
                                          const float (&myy)[ROWS],
                                          const float (&tdiag)[4]) {
#pragma unroll
  for (int rr = 0; rr < ROWS; ++rr) {
    const f32x2 mx = {myx[rr], myx[rr]};
    const f32x2 my = {myy[rr], myy[rr]};
#pragma unroll
    for (int q = 0; q < NP; ++q) {
      const f32x2 dx = px2[q] - mx;
      const f32x2 dy = py2[q] - my;
      f32x2 s = dx * dx;
      s = __builtin_elementwise_fma(dy, dy, s);
      const float d0 = __builtin_amdgcn_sqrtf(s.x);
      const float d1 = __builtin_amdgcn_sqrtf(s.y);
      float v0 = SIGMA_SQ * __builtin_amdgcn_exp2f(-d0);
      float v1 = SIGMA_SQ * __builtin_amdgcn_exp2f(-d1);
      if ((2 * q) % ROWS == rr)     v0 += tdiag[(2 * q) / ROWS];
      if ((2 * q + 1) % ROWS == rr) v1 += tdiag[(2 * q + 1) / ROWS];
      a2[rr][q].x = v0; a2[rr][q].y = v1;
    }
  }
}

// Dense 4-pass LDS-transpose epilogue (R14-identical).
__device__ __forceinline__ void epilogue(float* wbuf,
                                         const f32x2 (&a2)[ROWS][NP],
                                         float* __restrict__ out, int mbase,
                                         int B, int g, int o, int lane,
                                         int m) {
  if (mbase + GROUPS <= B) {
#pragma unroll
    for (int p = 0; p < 4; ++p) {
      if ((g >> 2) == p) {
        float* dst = wbuf + (g & 3) * (N * N) + o * (ROWS * N);
#pragma unroll
        for (int rr = 0; rr < ROWS; ++rr) {
#pragma unroll
          for (int q = 0; q < N / 4; ++q) {
            *(float4*)&dst[rr * N + 4 * q] =
                make_float4(a2[rr][2 * q].x, a2[rr][2 * q].y,
                            a2[rr][2 * q + 1].x, a2[rr][2 * q + 1].y);
          }
        }
      }
      LGKM_FENCE();
      float* gout = out + (size_t)(mbase + 4 * p) * (N * N);
#pragma unroll
      for (int s = 0; s < 6; ++s) {
        const float4 v = *(const float4*)&wbuf[lane * 4 + s * 256];
        *(float4*)&gout[lane * 4 + s * 256] = v;
      }
      if (lane < 16) {
        const float4 v = *(const float4*)&wbuf[lane * 4 + 6 * 256];
        *(float4*)&gout[lane * 4 + 6 * 256] = v;
      }
      LGKM_FENCE();
    }
  } else if (m < B) {
    float* om = out + (size_t)m * (N * N) + (ROWS * o) * N;
#pragma unroll
    for (int rr = 0; rr < ROWS; ++rr) {
#pragma unroll
      for (int q = 0; q < N / 4; ++q) {
        *(float4*)&om[rr * N + 4 * q] =
            make_float4(a2[rr][2 * q].x, a2[rr][2 * q].y,
                        a2[rr][2 * q + 1].x, a2[rr][2 * q + 1].y);
      }
    }
  }
}

__global__ __launch_bounds__(256, 2) void invcov_kernel(
    const float* __restrict__ pos, float* __restrict__ out, int B) {
  // Per-wave: 2.56 KB t1-points buffer + 6.4 KB transpose buffer.
  __shared__ float lds[WAVES_PER_BLOCK][PTS_FLOATS + WBUF_FLOATS];

  const int tid  = threadIdx.x;
  const int lane = tid & 63;
  const int wave = tid >> 6;
  const int g    = lane >> 2;
  const int o    = lane & 3;
  const int mbase0 = blockIdx.x * MATS_PER_BLOCK + wave * MATS_PER_WAVE;
  const int mbase1 = mbase0 + GROUPS;
  const int m0 = mbase0 + g;
  const int m1 = mbase1 + g;
  float* pts  = &lds[wave][0];
  float* wbuf = &lds[wave][PTS_FLOATS];

  // --- 1. Stage t1's 16 matrices of points into LDS: 4 global_load_lds,
  // zero VGPR state, issued BEFORE any store enters the vmcnt queue.
  {
    const int src_m = (mbase1 <= B - GROUPS) ? mbase1 : (B - GROUPS);
    const float* gsrc = pos + (size_t)src_m * (2 * N);
    __builtin_amdgcn_global_load_lds(
        (const __attribute__((address_space(1))) void*)(gsrc + lane * 4),
        (__attribute__((address_space(3))) void*)(pts), 16, 0, 0);
    __builtin_amdgcn_global_load_lds(
        (const __attribute__((address_space(1))) void*)(gsrc + 256 + lane * 4),
        (__attribute__((address_space(3))) void*)(pts + 256), 16, 0, 0);
    __builtin_amdgcn_global_load_lds(
        (const __attribute__((address_space(1))) void*)(gsrc + 512 + lane),
        (__attribute__((address_space(3))) void*)(pts + 512), 4, 0, 0);
    __builtin_amdgcn_global_load_lds(
        (const __attribute__((address_space(1))) void*)(gsrc + 576 + lane),
        (__attribute__((address_space(3))) void*)(pts + 576), 4, 0, 0);
  }
  SCHED_FENCE();

  float tdiag[4], ofl[4];
#pragma unroll
  for (int t = 0; t < 4; ++t) {
    const bool is = (o == t);
    tdiag[t] = is ? (TAU * SIGMA_SQ) : 0.0f;
    ofl[t]   = is ? 1.0f : 0.0f;
  }

  // --- 2. Tile 0: global loads -> regs, build, GJ.
  f32x2 px2[NP], py2[NP];
  float myx[ROWS], myy[ROWS];
  {
    const int mc0 = (m0 < B) ? m0 : (B - 1);
    const float* pm = pos + (size_t)mc0 * (2 * N);
    const float4* pv = (const float4*)pm;
#pragma unroll
    for (int q = 0; q < NP; ++q) {
      const float4 p = pv[q];
      px2[q].x = p.x * CSCALE; px2[q].y = p.z * CSCALE;
      py2[q].x = p.y * CSCALE; py2[q].y = p.w * CSCALE;
    }
    const float2* pm2 = (const float2*)pm;
#pragma unroll
    for (int rr = 0; rr < ROWS; ++rr) {
      const float2 p = pm2[ROWS * o + rr];
      myx[rr] = p.x * CSCALE; myy[rr] = p.y * CSCALE;
    }
  }
  f32x2 a2[ROWS][NP];
  build_cov(a2, px2, py2, myx, myy, tdiag);
  gj_all(a2, o, ofl);

  // --- 3. Fence: retire the gll (and long-done t0 loads). NO stores are
  // outstanding yet, so this vmcnt(0) is instant -- the R9 trap avoided.
  SCHED_FENCE();
  asm volatile("s_waitcnt vmcnt(0)" ::: "memory");
  SCHED_FENCE();

  // --- 4. Tile 0 epilogue: 28 stores, fire-and-forget.
  epilogue(wbuf, a2, out, mbase0, B, g, o, lane, m0);

  // --- 5. Tile 1: points from LDS (ds_read: lgkm-only, NO vmcnt dependency
  // -> t0's stores keep draining under this entire build+GJ).
  {
    const float4* pv = (const float4*)(pts + g * (2 * N));
#pragma unroll
    for (int q = 0; q < NP; ++q) {
      const float4 p = pv[q];
      px2[q].x = p.x * CSCALE; px2[q].y = p.z * CSCALE;
      py2[q].x = p.y * CSCALE; py2[q].y = p.w * CSCALE;
    }
    const float2* pm2 = (const float2*)(pts + g * (2 * N));
#pragma unroll
    for (int rr = 0; rr < ROWS; ++rr) {
      const float2 p = pm2[ROWS * o + rr];
      myx[rr] = p.x * CSCALE; myy[rr] = p.y * CSCALE;
    }
  }
  build_cov(a2, px2, py2, myx, myy, tdiag);
  gj_all(a2, o, ofl);

  // --- 6. Tile 1 epilogue; endpgm drains t1's stores (+ any t0 remnant).
  epilogue(wbuf, a2, out, mbase1, B, g, o, lane, m1);
}

}  // namespace

extern "C" void kernel_launch(void* const* d_in, const int* in_sizes, int n_in,
                              void* d_out, int out_size, void* d_ws, size_t ws_size,
                              hipStream_t stream) {
  const float* pos = (const float*)d_in[0];   // [B, 40] f32
  // d_in[1] (edge_list, int64) is unused by the reference computation.
  float* out = (float*)d_out;                 // [B, 20, 20] f32
  const int B = in_sizes[0] / (2 * N);
  const int blocks = (B + MATS_PER_BLOCK - 1) / MATS_PER_BLOCK;
  invcov_kernel<<<blocks, 256, 0, stream>>>(pos, out, B);
}

// Round 19
// 93.515 us; speedup vs baseline: 1.0447x; 1.0447x over previous
//
#include <hip/hip_runtime.h>

namespace {

constexpr int N = 20;                  // NEIGHBOR_SIZE
constexpr int ROWS = 5;                // rows per lane
constexpr int NP = N / 2;              // 10 column-pairs per row
constexpr int GROUPS = 16;             // 4-lane quads per wave = 16 matrices/wave
constexpr int WAVES_PER_BLOCK = 4;     // 256 threads
constexpr int MATS_PER_BLOCK = GROUPS * WAVES_PER_BLOCK;  // 64 -> 3125 blocks
constexpr float SIGMA_SQ = 1.0f;
constexpr float PHI = 0.5f;
constexpr float TAU = 0.1f;
constexpr float CSCALE = 0.72134752f;  // PHI * log2(e)

typedef float f32x2 __attribute__((ext_vector_type(2)));

// Broadcast lane (quadbase|SRC) to all 4 lanes of each quad -- ds_swizzle
// BitMode: new_lane = ((lane & 0x1C) | SRC). Executes on the LDS pipe
// (which is ~idle), NOT the VALU pipe (which is the wall): R18 post-mortem
// showed the kernel is VALU-issue-bound, so the 400 DPP movs/wave were 19%
// of the critical pipe. No LDS storage, no fences, same semantics.
template <int SRC>
__device__ __forceinline__ float qbcast(float x) {
  constexpr int OFF = (SRC << 5) | 0x1C;   // xor=0 | or=SRC | and=0x1C
  return __builtin_bit_cast(
      float, __builtin_amdgcn_ds_swizzle(__builtin_bit_cast(int, x), OFF));
}

// One Gauss-Jordan step on the PACKED tableau a2[5][10] (v_pk_fma_f32).
// K template => every register index compile-time (rule #20).
template <int K>
__device__ __forceinline__ void gj_step(f32x2 (&a2)[ROWS][NP], int o,
                                        const float (&ofl)[4]) {
  constexpr int KO = K / ROWS;         // owner lane of row K
  constexpr int KR = K % ROWS;         // owner-local row index
  constexpr int KP = K / 2;            // column-pair of K
  constexpr int KE = K % 2;            // element within pair

  f32x2 r2[NP];
#pragma unroll
  for (int q = 0; q < NP; ++q) {
    r2[q].x = qbcast<KO>(a2[KR][q].x);
    r2[q].y = qbcast<KO>(a2[KR][q].y);
  }
  const float rK = KE ? r2[KP].y : r2[KP].x;
  const float ip = __builtin_amdgcn_rcpf(rK);
  const float fpiv = 1.0f - ip;

#pragma unroll
  for (int rr = 0; rr < ROWS; ++rr) {
    const float aK = KE ? a2[rr][KP].y : a2[rr][KP].x;
    float f = aK * ip;
    if (rr == KR) f = (o == KO) ? fpiv : f;  // one cndmask, only on row KR
    const float nf = -f;
    const f32x2 nf2 = {nf, nf};
    // 10 pk-FMAs; element K's pair computes a garbage lane, fixed below.
#pragma unroll
    for (int q = 0; q < NP; ++q) {
      a2[rr][q] = __builtin_elementwise_fma(nf2, r2[q], a2[rr][q]);
    }
    if (KE) a2[rr][KP].y = nf; else a2[rr][KP].x = nf;  // col K: -A[i][K]/p
  }
  // owner diag: (1/p - 1) + 1 = 1/p
  if (KE) a2[KR][KP].y += ofl[KO]; else a2[KR][KP].x += ofl[KO];
}

__global__ __launch_bounds__(256, 2) void invcov_kernel(
    const float* __restrict__ pos, float* __restrict__ out, int B) {
  // Per-wave 6.4 KB transpose buffer (4 matrices x 400 floats), 4 passes.
  // Wave-local only -> lgkmcnt fences (R7 lesson: fences ARE required).
  __shared__ float lds[WAVES_PER_BLOCK][4 * N * N];

  const int tid  = threadIdx.x;
  const int lane = tid & 63;
  const int wave = tid >> 6;
  const int g    = lane >> 2;          // quad = matrix within wave, 0..15
  const int o    = lane & 3;           // lane within quad, owns rows 5o..5o+4
  const int mwave0 = blockIdx.x * MATS_PER_BLOCK + wave * GROUPS;
  const int m    = mwave0 + g;
  const int mc   = (m < B) ? m : (B - 1);

  const float* pm = pos + (size_t)mc * (2 * N);

  // 20 points in registers as column-PAIRS, pre-scaled by CSCALE.
  f32x2 px2[NP], py2[NP];
  {
    const float4* pv = (const float4*)pm;
#pragma unroll
    for (int q = 0; q < NP; ++q) {
      const float4 p = pv[q];              // cols 2q (x,y) and 2q+1 (z,w)
      px2[q].x = p.x * CSCALE; px2[q].y = p.z * CSCALE;
      py2[q].x = p.y * CSCALE; py2[q].y = p.w * CSCALE;
    }
  }
  // My 5 rows' coords: runtime offset -> tiny L1-hit loads, no reg-indexing.
  float myx[ROWS], myy[ROWS];
  {
    const float2* pm2 = (const float2*)pm;
#pragma unroll
    for (int rr = 0; rr < ROWS; ++rr) {
      const float2 p = pm2[ROWS * o + rr];
      myx[rr] = p.x * CSCALE; myy[rr] = p.y * CSCALE;
    }
  }

  // Per-quad-lane constant masks, constant-indexed.
  float tdiag[4], ofl[4];
#pragma unroll
  for (int t = 0; t < 4; ++t) {
    const bool is = (o == t);
    tdiag[t] = is ? (TAU * SIGMA_SQ) : 0.0f;
    ofl[t]   = is ? 1.0f : 0.0f;
  }

  // Build my 5 rows (packed pairs): a = s^2 * 2^(-C*d) (+ tau*s^2 on diag).
  f32x2 a2[ROWS][NP];
#pragma unroll
  for (int rr = 0; rr < ROWS; ++rr) {
    const f32x2 mx = {myx[rr], myx[rr]};
    const f32x2 my = {myy[rr], myy[rr]};
#pragma unroll
    for (int q = 0; q < NP; ++q) {
      const f32x2 dx = px2[q] - mx;        // v_pk_add (neg mod)
      const f32x2 dy = py2[q] - my;
      f32x2 s = dx * dx;                   // v_pk_mul
      s = __builtin_elementwise_fma(dy, dy, s);  // v_pk_fma
      const float d0 = __builtin_amdgcn_sqrtf(s.x);
      const float d1 = __builtin_amdgcn_sqrtf(s.y);
      float v0 = SIGMA_SQ * __builtin_amdgcn_exp2f(-d0);
      float v1 = SIGMA_SQ * __builtin_amdgcn_exp2f(-d1);
      if ((2 * q) % ROWS == rr)     v0 += tdiag[(2 * q) / ROWS];
      if ((2 * q + 1) % ROWS == rr) v1 += tdiag[(2 * q + 1) / ROWS];
      a2[rr][q].x = v0; a2[rr][q].y = v1;
    }
  }

  // 20 explicit template steps: compile-time K everywhere.
  __builtin_amdgcn_s_setprio(1);
  gj_step<0>(a2, o, ofl);  gj_step<1>(a2, o, ofl);  gj_step<2>(a2, o, ofl);
  gj_step<3>(a2, o, ofl);  gj_step<4>(a2, o, ofl);  gj_step<5>(a2, o, ofl);
  gj_step<6>(a2, o, ofl);  gj_step<7>(a2, o, ofl);  gj_step<8>(a2, o, ofl);
  gj_step<9>(a2, o, ofl);  gj_step<10>(a2, o, ofl); gj_step<11>(a2, o, ofl);
  gj_step<12>(a2, o, ofl); gj_step<13>(a2, o, ofl); gj_step<14>(a2, o, ofl);
  gj_step<15>(a2, o, ofl); gj_step<16>(a2, o, ofl); gj_step<17>(a2, o, ofl);
  gj_step<18>(a2, o, ofl); gj_step<19>(a2, o, ofl);
  __builtin_amdgcn_s_setprio(0);

  float* wbuf = &lds[wave][0];

  if (mwave0 + GROUPS <= B) {
    // Dense epilogue (R8/R14-identical): 4 passes of 4 matrices via LDS.
#pragma unroll
    for (int p = 0; p < 4; ++p) {
      if ((g >> 2) == p) {
        float* dst = wbuf + (g & 3) * (N * N) + o * (ROWS * N);
#pragma unroll
        for (int rr = 0; rr < ROWS; ++rr) {
#pragma unroll
          for (int q = 0; q < N / 4; ++q) {   // float4 = pairs 2q, 2q+1
            *(float4*)&dst[rr * N + 4 * q] =
                make_float4(a2[rr][2 * q].x, a2[rr][2 * q].y,
                            a2[rr][2 * q + 1].x, a2[rr][2 * q + 1].y);
          }
        }
      }
      asm volatile("s_waitcnt lgkmcnt(0)" ::: "memory");

      float* gout = out + (size_t)(mwave0 + 4 * p) * (N * N);
#pragma unroll
      for (int s = 0; s < 6; ++s) {
        const float4 v = *(const float4*)&wbuf[lane * 4 + s * 256];
        *(float4*)&gout[lane * 4 + s * 256] = v;
      }
      if (lane < 16) {
        const float4 v = *(const float4*)&wbuf[lane * 4 + 6 * 256];
        *(float4*)&gout[lane * 4 + 6 * 256] = v;
      }
      // Reads must land in VGPRs before next pass overwrites the buffer.
      asm volatile("s_waitcnt lgkmcnt(0)" ::: "memory");
    }
  } else if (m < B) {
    // Rare tail wave: direct (slow) per-lane stores.
    float* om = out + (size_t)m * (N * N) + (ROWS * o) * N;
#pragma unroll
    for (int rr = 0; rr < ROWS; ++rr) {
#pragma unroll
      for (int q = 0; q < N / 4; ++q) {
        *(float4*)&om[rr * N + 4 * q] =
            make_float4(a2[rr][2 * q].x, a2[rr][2 * q].y,
                        a2[rr][2 * q + 1].x, a2[rr][2 * q + 1].y);
      }
    }
  }
}

}  // namespace

extern "C" void kernel_launch(void* const* d_in, const int* in_sizes, int n_in,
                              void* d_out, int out_size, void* d_ws, size_t ws_size,
                              hipStream_t stream) {
  const float* pos = (const float*)d_in[0];   // [B, 40] f32
  // d_in[1] (edge_list, int64) is unused by the reference computation.
  float* out = (float*)d_out;                 // [B, 20, 20] f32
  const int B = in_sizes[0] / (2 * N);
  const int blocks = (B + MATS_PER_BLOCK - 1) / MATS_PER_BLOCK;
  invcov_kernel<<<blocks, 256, 0, stream>>>(pos, out, B);
}

// Round 20
// 85.587 us; speedup vs baseline: 1.1415x; 1.0926x over previous
//
#include <hip/hip_runtime.h>

namespace {

constexpr int N = 20;                  // NEIGHBOR_SIZE
constexpr int ROWS = 5;                // rows per lane
constexpr int NP = N / 2;              // 10 column-pairs per row
constexpr int GROUPS = 16;             // 4-lane quads per wave = 16 matrices/wave
constexpr int WAVES_PER_BLOCK = 4;     // 256 threads
constexpr int MATS_PER_BLOCK = GROUPS * WAVES_PER_BLOCK;  // 64 -> 3125 blocks
constexpr float SIGMA_SQ = 1.0f;
constexpr float PHI = 0.5f;
constexpr float TAU = 0.1f;
constexpr float CSCALE = 0.72134752f;  // PHI * log2(e)

typedef float f32x2 __attribute__((ext_vector_type(2)));

// Broadcast lane SRC of each 4-lane quad to all 4 lanes: DPP quad_perm.
// (R19 measured: ds_swizzle variant is 8us SLOWER -- same issue-port cost
// plus lgkmcnt waits. DPP is the right form.)
template <int SRC>
__device__ __forceinline__ float qbcast(float x) {
  constexpr int CTRL = SRC * 0x55;
  return __builtin_bit_cast(
      float, __builtin_amdgcn_mov_dpp(__builtin_bit_cast(int, x), CTRL, 0xF,
                                      0xF, true));
}

// One Gauss-Jordan step on the PACKED tableau a2[5][10] (f32x2 pairs ->
// v_pk_fma_f32, 2 FLOP/inst). K template => every index compile-time.
template <int K>
__device__ __forceinline__ void gj_step(f32x2 (&a2)[ROWS][NP], int o,
                                        const float (&ofl)[4]) {
  constexpr int KO = K / ROWS;         // owner lane of row K
  constexpr int KR = K % ROWS;         // owner-local row index
  constexpr int KP = K / 2;            // column-pair of K
  constexpr int KE = K % 2;            // element within pair

  f32x2 r2[NP];
#pragma unroll
  for (int q = 0; q < NP; ++q) {
    r2[q].x = qbcast<KO>(a2[KR][q].x);
    r2[q].y = qbcast<KO>(a2[KR][q].y);
  }
  const float rK = KE ? r2[KP].y : r2[KP].x;
  const float ip = __builtin_amdgcn_rcpf(rK);
  const float fpiv = 1.0f - ip;

#pragma unroll
  for (int rr = 0; rr < ROWS; ++rr) {
    const float aK = KE ? a2[rr][KP].y : a2[rr][KP].x;
    float f = aK * ip;
    if (rr == KR) f = (o == KO) ? fpiv : f;  // one cndmask, only on row KR
    const float nf = -f;
    const f32x2 nf2 = {nf, nf};
    // 10 pk-FMAs; element K's pair computes a garbage lane, fixed below.
#pragma unroll
    for (int q = 0; q < NP; ++q) {
      a2[rr][q] = __builtin_elementwise_fma(nf2, r2[q], a2[rr][q]);
    }
    if (KE) a2[rr][KP].y = nf; else a2[rr][KP].x = nf;  // col K: -A[i][K]/p
  }
  // owner diag: (1/p - 1) + 1 = 1/p
  if (KE) a2[KR][KP].y += ofl[KO]; else a2[KR][KP].x += ofl[KO];
}

__global__ __launch_bounds__(256, 2) void invcov_kernel(
    const float* __restrict__ pos, float* __restrict__ out, int B) {
  // Per-wave 6.4 KB transpose buffer (4 matrices x 400 floats), 4 passes.
  // Wave-local only -> lgkmcnt fences (R7 lesson: fences ARE required).
  __shared__ float lds[WAVES_PER_BLOCK][4 * N * N];

  const int tid  = threadIdx.x;
  const int lane = tid & 63;
  const int wave = tid >> 6;
  const int g    = lane >> 2;          // quad = matrix within wave, 0..15
  const int o    = lane & 3;           // lane within quad, owns rows 5o..5o+4
  const int mwave0 = blockIdx.x * MATS_PER_BLOCK + wave * GROUPS;
  const int m    = mwave0 + g;
  const int mc   = (m < B) ? m : (B - 1);

  const float* pm = pos + (size_t)mc * (2 * N);

  // 20 points in registers as column-PAIRS, pre-scaled by CSCALE.
  f32x2 px2[NP], py2[NP];
  {
    const float4* pv = (const float4*)pm;
#pragma unroll
    for (int q = 0; q < NP; ++q) {
      const float4 p = pv[q];              // cols 2q (x,y) and 2q+1 (z,w)
      px2[q].x = p.x * CSCALE; px2[q].y = p.z * CSCALE;
      py2[q].x = p.y * CSCALE; py2[q].y = p.w * CSCALE;
    }
  }
  // My 5 rows' coords: runtime offset -> tiny L1-hit loads, no reg-indexing.
  float myx[ROWS], myy[ROWS];
  {
    const float2* pm2 = (const float2*)pm;
#pragma unroll
    for (int rr = 0; rr < ROWS; ++rr) {
      const float2 p = pm2[ROWS * o + rr];
      myx[rr] = p.x * CSCALE; myy[rr] = p.y * CSCALE;
    }
  }

  // Per-quad-lane constant masks, constant-indexed.
  float tdiag[4], ofl[4];
#pragma unroll
  for (int t = 0; t < 4; ++t) {
    const bool is = (o == t);
    tdiag[t] = is ? (TAU * SIGMA_SQ) : 0.0f;
    ofl[t]   = is ? 1.0f : 0.0f;
  }

  // Build my 5 rows (packed pairs): a = s^2 * 2^(-C*d) (+ tau*s^2 on diag).
  f32x2 a2[ROWS][NP];
#pragma unroll
  for (int rr = 0; rr < ROWS; ++rr) {
    const f32x2 mx = {myx[rr], myx[rr]};
    const f32x2 my = {myy[rr], myy[rr]};
#pragma unroll
    for (int q = 0; q < NP; ++q) {
      const f32x2 dx = px2[q] - mx;        // v_pk_add (neg mod)
      const f32x2 dy = py2[q] - my;
      f32x2 s = dx * dx;                   // v_pk_mul
      s = __builtin_elementwise_fma(dy, dy, s);  // v_pk_fma
      const float d0 = __builtin_amdgcn_sqrtf(s.x);
      const float d1 = __builtin_amdgcn_sqrtf(s.y);
      float v0 = SIGMA_SQ * __builtin_amdgcn_exp2f(-d0);
      float v1 = SIGMA_SQ * __builtin_amdgcn_exp2f(-d1);
      if ((2 * q) % ROWS == rr)     v0 += tdiag[(2 * q) / ROWS];
      if ((2 * q + 1) % ROWS == rr) v1 += tdiag[(2 * q + 1) / ROWS];
      a2[rr][q].x = v0; a2[rr][q].y = v1;
    }
  }

  // 20 explicit template steps: compile-time K everywhere.
  __builtin_amdgcn_s_setprio(1);
  gj_step<0>(a2, o, ofl);  gj_step<1>(a2, o, ofl);  gj_step<2>(a2, o, ofl);
  gj_step<3>(a2, o, ofl);  gj_step<4>(a2, o, ofl);  gj_step<5>(a2, o, ofl);
  gj_step<6>(a2, o, ofl);  gj_step<7>(a2, o, ofl);  gj_step<8>(a2, o, ofl);
  gj_step<9>(a2, o, ofl);  gj_step<10>(a2, o, ofl); gj_step<11>(a2, o, ofl);
  gj_step<12>(a2, o, ofl); gj_step<13>(a2, o, ofl); gj_step<14>(a2, o, ofl);
  gj_step<15>(a2, o, ofl); gj_step<16>(a2, o, ofl); gj_step<17>(a2, o, ofl);
  gj_step<18>(a2, o, ofl); gj_step<19>(a2, o, ofl);
  __builtin_amdgcn_s_setprio(0);

  float* wbuf = &lds[wave][0];

  if (mwave0 + GROUPS <= B) {
    // Dense epilogue (R8-identical): 4 passes of 4 matrices via LDS.
#pragma unroll
    for (int p = 0; p < 4; ++p) {
      if ((g >> 2) == p) {
        float* dst = wbuf + (g & 3) * (N * N) + o * (ROWS * N);
#pragma unroll
        for (int rr = 0; rr < ROWS; ++rr) {
#pragma unroll
          for (int q = 0; q < N / 4; ++q) {   // float4 = pairs 2q, 2q+1
            *(float4*)&dst[rr * N + 4 * q] =
                make_float4(a2[rr][2 * q].x, a2[rr][2 * q].y,
                            a2[rr][2 * q + 1].x, a2[rr][2 * q + 1].y);
          }
        }
      }
      asm volatile("s_waitcnt lgkmcnt(0)" ::: "memory");

      float* gout = out + (size_t)(mwave0 + 4 * p) * (N * N);
#pragma unroll
      for (int s = 0; s < 6; ++s) {
        const float4 v = *(const float4*)&wbuf[lane * 4 + s * 256];
        *(float4*)&gout[lane * 4 + s * 256] = v;
      }
      if (lane < 16) {
        const float4 v = *(const float4*)&wbuf[lane * 4 + 6 * 256];
        *(float4*)&gout[lane * 4 + 6 * 256] = v;
      }
      // Reads must land in VGPRs before next pass overwrites the buffer.
      asm volatile("s_waitcnt lgkmcnt(0)" ::: "memory");
    }
  } else if (m < B) {
    // Rare tail wave: direct (slow) per-lane stores.
    float* om = out + (size_t)m * (N * N) + (ROWS * o) * N;
#pragma unroll
    for (int rr = 0; rr < ROWS; ++rr) {
#pragma unroll
      for (int q = 0; q < N / 4; ++q) {
        *(float4*)&om[rr * N + 4 * q] =
            make_float4(a2[rr][2 * q].x, a2[rr][2 * q].y,
                        a2[rr][2 * q + 1].x, a2[rr][2 * q + 1].y);
      }
    }
  }
}

}  // namespace

extern "C" void kernel_launch(void* const* d_in, const int* in_sizes, int n_in,
                              void* d_out, int out_size, void* d_ws, size_t ws_size,
                              hipStream_t stream) {
  const float* pos = (const float*)d_in[0];   // [B, 40] f32
  // d_in[1] (edge_list, int64) is unused by the reference computation.
  float* out = (float*)d_out;                 // [B, 20, 20] f32
  const int B = in_sizes[0] / (2 * N);
  const int blocks = (B + MATS_PER_BLOCK - 1) / MATS_PER_BLOCK;
  invcov_kernel<<<blocks, 256, 0, stream>>>(pos, out, B);
}